// Round 18
// baseline (123.656 us; speedup 1.0000x reference)
//
#include <hip/hip_runtime.h>
#include <hip/hip_bf16.h>

// LS2T iterated sums (ORDER=3): B=64, T=4096, D=128, F=64, C=6.
// m_c(t,f) = seq[b,t,:]·kernel[c,:,f] + bias[c,f]
// Y1 = sum m0; Y2 = sum m2*cumx(m1); Y3 = sum m5*cumx(m4*cumx(m3))
//
// Round 18: NO LDS, NO __syncthreads. Each lane loads its MFMA A-fragment
// directly from global (8 x dwordx4 at immediate offsets inside its own
// 512B row); all 4 waves of a block read identical addresses -> L1 dedup;
// cg-partner blocks share the XCD's L2 (bijective XCD swizzle). Depth-2
// register prefetch (fA/fB) with counted VW(8); bare s_barrier every 2
// chunks only for L1 temporal alignment. cg-split blocks (cg0: c0..2 ->
// Y1,Y2; cg1: c3..5 -> Y3), B-frags in AGPRs, unified 6-reg scan.

#define B_ 64
#define T_ 4096
#define D_ 128
#define F_ 64
#define TB 512             // t per (b,tg) span
#define TGROUPS (T_ / TB)  // 8
#define NITER 32           // 16-t chunks per span
#define TPB 256
#define NBLK (B_ * TGROUPS * 2)   // 1024

typedef __attribute__((ext_vector_type(8))) short short8v;
typedef __attribute__((ext_vector_type(4))) float f32x4;

__device__ __forceinline__ unsigned short bfb(float x) {
    __hip_bfloat16 h = __float2bfloat16(x);   // RNE (B operand only)
    unsigned short u;
    __builtin_memcpy(&u, &h, 2);
    return u;
}

#define VW(n) asm volatile("s_waitcnt vmcnt(" #n ")" ::: "memory")

__global__ __launch_bounds__(TPB, 3)
void ls2t_kernel(const float* __restrict__ seq,
                 const float* __restrict__ kern,
                 const float* __restrict__ bias,
                 float* __restrict__ ws)
{
    const int tid = threadIdx.x;
    // bijective XCD swizzle: logical-consecutive blocks (cg pairs of the same
    // span) land on the same XCD -> A re-reads dedup in that XCD's L2.
    const int bid     = blockIdx.x;                 // 0..1023
    const int logical = (bid & 7) * (NBLK / 8) + (bid >> 3);
    const int cg = logical & 1;        // 0 -> c0..2 (Y1,Y2), 1 -> c3..5 (Y3)
    const int tg = (logical >> 1) & (TGROUPS - 1);
    const int b  = logical >> 4;

    const int lane = tid & 63;
    const int wv   = tid >> 6;         // f-wave 0..3
    const int fr   = lane & 15;
    const int lg   = lane >> 4;
    const int f    = wv * 16 + fr;

    // ---- B fragments in registers (mfma B: col=lane&15=f, k=(lane>>4)*8+j)
    short8v bfrag[3][4];
    float bc[3];
    #pragma unroll
    for (int cc = 0; cc < 3; ++cc) {
        const int c = cg * 3 + cc;
        bc[cc] = bias[c * F_ + f];
        #pragma unroll
        for (int ks = 0; ks < 4; ++ks) {
            const float* kp = kern + ((size_t)c * D_ + ks * 32 + lg * 8) * F_ + f;
            short8v bf;
            #pragma unroll
            for (int j = 0; j < 8; ++j) bf[j] = (short)bfb(kp[(size_t)j * F_]);
            bfrag[cc][ks] = bf;
        }
    }

    // ---- per-lane A geometry ----
    // MFMA A: lane (fr,lg) needs A[row=fr][k=ks*32+lg*8 .. +8] per ks.
    // Row fr of chunk i is t_local = (fr>>2)*128 + i*4 + (fr&3) -> lane-group
    // lg owns contiguous t-stripe [lg*128,+128); in-lane t monotone.
    // Per chunk the lane reads 8 float4 at float4-offsets {0,1,8,9,16,17,24,25}
    // from (row_ptr + lg*8 floats) -- all compile-time immediates.
    const float* gp = seq
        + ((size_t)b * T_ + (size_t)tg * TB + (fr >> 2) * 128 + (fr & 3)) * D_
        + lg * 8;

    float4 fA[8], fB[8];
    auto LD8 = [&](const float* p, float4* A) {
        const float4* p4 = reinterpret_cast<const float4*>(p);
        A[0] = p4[0];  A[1] = p4[1];
        A[2] = p4[8];  A[3] = p4[9];
        A[4] = p4[16]; A[5] = p4[17];
        A[6] = p4[24]; A[7] = p4[25];
    };

    // unified scan state (cg0: a0=x0,s1=x1,s2=x2,q2=x4; cg1: su..qwvu=x0..x5)
    float x0 = 0.f, x1 = 0.f, x2 = 0.f, x3 = 0.f, x4 = 0.f, x5 = 0.f;

    auto compute = [&](const float4* A) {
        f32x4 acc[3];
        #pragma unroll
        for (int cc = 0; cc < 3; ++cc)
            acc[cc] = (f32x4){bc[cc], bc[cc], bc[cc], bc[cc]};

        #pragma unroll
        for (int ks = 0; ks < 4; ++ks) {
            uint4 pk;
            pk.x = __builtin_amdgcn_perm(__float_as_uint(A[2 * ks].y),
                                         __float_as_uint(A[2 * ks].x), 0x07060302u);
            pk.y = __builtin_amdgcn_perm(__float_as_uint(A[2 * ks].w),
                                         __float_as_uint(A[2 * ks].z), 0x07060302u);
            pk.z = __builtin_amdgcn_perm(__float_as_uint(A[2 * ks + 1].y),
                                         __float_as_uint(A[2 * ks + 1].x), 0x07060302u);
            pk.w = __builtin_amdgcn_perm(__float_as_uint(A[2 * ks + 1].w),
                                         __float_as_uint(A[2 * ks + 1].z), 0x07060302u);
            short8v a = *reinterpret_cast<short8v*>(&pk);
            #pragma unroll
            for (int cc = 0; cc < 3; ++cc)
                acc[cc] = __builtin_amdgcn_mfma_f32_16x16x32_bf16(
                    a, bfrag[cc][ks], acc[cc], 0, 0, 0);
        }

        // lane owns t = tg*512 + lg*128 + i*4 + r  -> chain in-lane
        #pragma unroll
        for (int r = 0; r < 4; ++r) {
            float p = acc[0][r], q = acc[1][r], rr = acc[2][r];
            x5 = fmaf(rr, x3, x5);   // qwvu += m5*qvu            (cg1)
            x4 = fmaf(rr, x1, x4);   // q2 += m2*s1 / qwv += m5*sv
            x3 = fmaf(q,  x0, x3);   // qvu += m4*su              (cg1)
            x2 += rr;                // s2 / sw
            x1 += q;                 // s1 / sv
            x0 += p;                 // a0 / su
        }
    };

    // ---- free-running pipeline: depth-2 reg prefetch, counted VW(8) ----
    LD8(gp, fA);
    LD8(gp + 4 * D_, fB);
    gp += 8 * D_;

    #pragma unroll 1
    for (int i = 0; i <= NITER - 4; i += 2) {
        VW(8);                       // fA (chunk i) landed; fB in flight
        compute(fA);
        LD8(gp, fA);                 // chunk i+2
        VW(8);                       // fB (chunk i+1) landed
        compute(fB);
        LD8(gp + 4 * D_, fB);        // chunk i+3
        gp += 8 * D_;
        asm volatile("s_barrier");   // bare sync: keep block's waves L1-close
    }
    // epilogue: chunks 30,31 already loaded
    VW(8); compute(fA);
    VW(0); compute(fB);

    // ---- merge the 4 lane-group stripes (time order: lg ascending) ----
    #pragma unroll
    for (int m = 16; m <= 32; m <<= 1) {
        float o0 = __shfl_xor(x0, m), o1 = __shfl_xor(x1, m);
        float o2 = __shfl_xor(x2, m), o3 = __shfl_xor(x3, m);
        float o4 = __shfl_xor(x4, m), o5 = __shfl_xor(x5, m);
        const bool up = (lane & m) != 0;   // this lane holds the LATER segment
        float A0 = up ? o0 : x0, B0 = up ? x0 : o0;
        float A1 = up ? o1 : x1, B1 = up ? x1 : o1;
        float A2 = up ? o2 : x2, B2 = up ? x2 : o2;
        float A3 = up ? o3 : x3, B3 = up ? x3 : o3;
        float A4 = up ? o4 : x4, B4 = up ? x4 : o4;
        float A5 = up ? o5 : x5, B5 = up ? x5 : o5;
        x5 = A5 + B5 + A3 * B2 + A0 * B4;
        x4 = A4 + B4 + A1 * B2;
        x3 = A3 + B3 + A0 * B1;
        x2 = A2 + B2;
        x1 = A1 + B1;
        x0 = A0 + B0;
    }

    if (lg == 0) {
        float* wp = ws + (((size_t)b * TGROUPS + tg) * F_ + f) * 10;
        if (cg == 0) {
            wp[0] = x0; wp[1] = x1; wp[2] = x2; wp[3] = x4;
        } else {
            wp[4] = x0; wp[5] = x1; wp[6] = x2;
            wp[7] = x3; wp[8] = x4; wp[9] = x5;
        }
    }
}

struct St { float a0, s1, s2, q2, su, sv, sw, qvu, qwv, qwvu; };

__device__ __forceinline__ St mergeSt(const St& A, const St& B) {
    St r;
    r.a0   = A.a0 + B.a0;
    r.q2   = A.q2 + B.q2 + A.s1 * B.s2;
    r.s1   = A.s1 + B.s1;
    r.s2   = A.s2 + B.s2;
    r.qwvu = A.qwvu + B.qwvu + A.qvu * B.sw + A.su * B.qwv;
    r.qwv  = A.qwv + B.qwv + A.sv * B.sw;
    r.qvu  = A.qvu + B.qvu + A.su * B.sv;
    r.su   = A.su + B.su;
    r.sv   = A.sv + B.sv;
    r.sw   = A.sw + B.sw;
    return r;
}

__global__ __launch_bounds__(64)
void ls2t_fold_kernel(const float* __restrict__ ws, float* __restrict__ out)
{
    const int b = blockIdx.x;
    const int f = threadIdx.x;
    St A = {0, 0, 0, 0, 0, 0, 0, 0, 0, 0};
    #pragma unroll
    for (int g = 0; g < TGROUPS; ++g) {
        const float* rp = ws + (((size_t)b * TGROUPS + g) * F_ + f) * 10;
        St r = {rp[0], rp[1], rp[2], rp[3], rp[4],
                rp[5], rp[6], rp[7], rp[8], rp[9]};
        A = mergeSt(A, r);
    }
    float* op = out + ((size_t)b * F_ + f) * 3;
    op[0] = A.a0;
    op[1] = A.q2;
    op[2] = A.qwvu;
}

extern "C" void kernel_launch(void* const* d_in, const int* in_sizes, int n_in,
                              void* d_out, int out_size, void* d_ws, size_t ws_size,
                              hipStream_t stream) {
    const float* seq  = (const float*)d_in[0];
    const float* kern = (const float*)d_in[1];
    const float* bias = (const float*)d_in[2];
    float* out = (float*)d_out;
    float* ws  = (float*)d_ws;   // B_*TGROUPS*F_*10*4 = 1.31 MB

    ls2t_kernel<<<NBLK, TPB, 0, stream>>>(seq, kern, bias, ws);
    ls2t_fold_kernel<<<B_, F_, 0, stream>>>(ws, out);
}